// Round 4
// baseline (7075.000 us; speedup 1.0000x reference)
//
#include <hip/hip_runtime.h>
#include <hip/hip_bf16.h>

// LSTM N=64, T=512, D=1024, H=1024 — round 4: round-3 design, de-risked.
// Round-2 counters: Occupancy 12.4% (1 wave/SIMD), FETCH 3.54 GB (Wt refetched each
// step), MfmaUtil 4.3% -> latency-bound. Levers kept from round 3:
//   * weight fragments live in 128 VGPRs per lane (recurrence has zero global weight
//     loads)
//   * 512-thread WGs: waves 0-3 = x-GEMM (K 0..1023) + epilogue + xb prefetch;
//     waves 4-7 = h-GEMM (K 1024..2047) + h spin/stage. 2 waves/SIMD.
// De-risked vs round 3: no hready handoff (all h-waves spin on global flags,
// round-2-proven), un-swizzled 1032-stride LDS (round-2-proven), poison timeout 1<<16
// (fast-fail ~seconds, can't kill the container).
// ws: Wt 16MB | xb 64MB | hb 2x128KB | flags 512KB

#define T_T 512
#define KTOT 2048

typedef short bf16x8 __attribute__((ext_vector_type(8)));
typedef float f32x4 __attribute__((ext_vector_type(4)));
typedef unsigned u32x4 __attribute__((ext_vector_type(4)));

union B8U { u32x4 u; bf16x8 v; };
union P4 { __hip_bfloat16 h[4]; uint2 u; };

// ---- Wt[a_col][k] = bf16([Wx;Wh][k][a_col]), 4096 x 2048 (proven) ----
__global__ __launch_bounds__(256) void prep_weights(const float* __restrict__ Wx,
                                                    const float* __restrict__ Wh,
                                                    __hip_bfloat16* __restrict__ Wt) {
  __shared__ float tile[64][65];
  int kb = blockIdx.x & 31;
  int cb = blockIdx.x >> 5;
  int k0 = kb << 6, c0 = cb << 6;
  const float* W = (k0 < 1024) ? Wx : Wh;
  int kr0 = k0 & 1023;
  int tid = threadIdx.x;
  int f4 = tid & 15;
  int i0 = tid >> 4;
  for (int p = 0; p < 4; ++p) {
    int i = i0 + (p << 4);
    float4 v = *(const float4*)(W + (size_t)(kr0 + i) * 4096 + c0 + (f4 << 2));
    tile[(f4 << 2) + 0][i] = v.x;
    tile[(f4 << 2) + 1][i] = v.y;
    tile[(f4 << 2) + 2][i] = v.z;
    tile[(f4 << 2) + 3][i] = v.w;
  }
  __syncthreads();
  for (int p = 0; p < 16; ++p) {
    int idx = (p << 8) + tid;
    int kl = idx & 63, cl = idx >> 6;
    Wt[(size_t)(c0 + cl) * KTOT + k0 + kl] = __float2bfloat16(tile[cl][kl]);
  }
}

// ---- x (64,512,1024) f32 -> xb (512,64,1024) bf16 ----
__global__ __launch_bounds__(256) void prep_xb(const float* __restrict__ x,
                                               __hip_bfloat16* __restrict__ xb) {
  int b = blockIdx.x;            // 32768 = 512*64
  int n = b & 63, t = b >> 6;
  const float4* src = (const float4*)(x + ((size_t)n * T_T + t) * 1024);
  __hip_bfloat16* dst = xb + ((size_t)t * 64 + n) * 1024;
  float4 v = src[threadIdx.x];
  P4 pk;
  pk.h[0] = __float2bfloat16(v.x);
  pk.h[1] = __float2bfloat16(v.y);
  pk.h[2] = __float2bfloat16(v.z);
  pk.h[3] = __float2bfloat16(v.w);
  *(uint2*)(dst + (threadIdx.x << 2)) = pk.u;
}

// ---- h0 -> bf16 into hb[0] ----
__global__ __launch_bounds__(256) void prep_state(const float* __restrict__ h0,
                                                  __hip_bfloat16* __restrict__ hb) {
  int i = blockIdx.x * 256 + threadIdx.x;   // 65536
  hb[i] = __float2bfloat16(h0[i]);
}

// ---- persistent LSTM ----
__global__ __launch_bounds__(512, 2) void lstm_persist(
    const __hip_bfloat16* __restrict__ xb,   // (512,64,1024)
    const float* __restrict__ bias,
    const __hip_bfloat16* __restrict__ Wt,   // (4096,2048)
    __hip_bfloat16* hb,                      // [2][64*1024]
    float* __restrict__ out,                 // (64,512,1024)
    unsigned* flags)                         // [512][4][64] counters (-> 4 each)
{
  // proven 1032-element row stride: 2064 B, 16B-aligned, <=2-way bank aliasing
  __shared__ __align__(16) __hip_bfloat16 AX[2][16][1032];  // x tile, double buffer
  __shared__ __align__(16) __hip_bfloat16 AH[16][1032];     // h tile
  __shared__ float gtX[4][16][17];
  __shared__ float gtH[4][16][17];

  const int tid  = threadIdx.x;
  const int cgrp = blockIdx.x & 63;   // h-cols [16*cgrp,+16)
  const int bg   = blockIdx.x >> 6;   // batch rows [16*bg,+16)
  const int rows0 = bg << 4;
  const int lane = tid & 63;
  const int wv   = tid >> 6;          // 0..7
  const int gate = wv & 3;
  const int half = wv >> 2;           // 0 = x-part (K 0..1023), 1 = h-part
  const int mcol = lane & 15;
  const int q    = lane >> 4;
  const int tid2 = tid & 255;

  // ---- weight fragments -> registers (32 x u32x4 = 128 VGPR), invariant over t ----
  u32x4 wfrag[32];
  {
    const __hip_bfloat16* wp = Wt
      + ((size_t)(gate << 10) + (cgrp << 4) + mcol) * (size_t)KTOT
      + (half << 10) + (q << 3);
    #pragma unroll
    for (int kk = 0; kk < 32; ++kk)
      wfrag[kk] = *(const u32x4*)(wp + (kk << 5));
  }

  // epilogue identity (x-waves = tid < 256)
  const int er = tid2 >> 4, ej = tid2 & 15;
  const int hcol = (cgrp << 4) + ej;
  const int rg = rows0 + er;
  float b_i = 0.f, b_f = 0.f, b_o = 0.f, b_g = 0.f;
  if (half == 0) {
    b_i = bias[hcol]; b_f = bias[1024 + hcol];
    b_o = bias[2048 + hcol]; b_g = bias[3072 + hcol];
  }
  float creg = 0.f;
  int poison = 0;

  // ---- prologue: x-waves stage xb_0 -> AX[0]; h-waves stage h0 -> AH ----
  if (half == 0) {
    const u32x4* src = (const u32x4*)(xb + (size_t)rows0 * 1024);
    #pragma unroll
    for (int p = 0; p < 8; ++p) {
      int r = (p << 1) + (tid2 >> 7), c8 = tid2 & 127;
      u32x4 v = src[r * 128 + c8];
      *(u32x4*)&AX[0][r][c8 << 3] = v;
    }
  } else {
    const u32x4* src = (const u32x4*)(hb + (size_t)rows0 * 1024);
    #pragma unroll
    for (int p = 0; p < 8; ++p) {
      int r = (p << 1) + (tid2 >> 7), c8 = tid2 & 127;
      u32x4 v = src[r * 128 + c8];
      *(u32x4*)&AH[r][c8 << 3] = v;
    }
  }
  __syncthreads();

  for (int t = 0; t < T_T; ++t) {
    // ---- phase 1: both GEMMs (LDS A-tile x reg-resident weights) ----
    {
      const __hip_bfloat16* L = (half == 0) ? &AX[t & 1][0][0] : &AH[0][0];
      f32x4 acc = {0.f, 0.f, 0.f, 0.f};
      #pragma unroll
      for (int kk = 0; kk < 32; ++kk) {
        B8U a, b;
        a.u = *(const u32x4*)(L + (size_t)mcol * 1032 + (kk << 5) + (q << 3));
        b.u = wfrag[kk];
        acc = __builtin_amdgcn_mfma_f32_16x16x32_bf16(a.v, b.v, acc, 0, 0, 0);
      }
      float (*gt)[16][17] = (half == 0) ? gtX : gtH;
      #pragma unroll
      for (int i = 0; i < 4; ++i)
        gt[gate][(q << 2) + i][mcol] = acc[i];
    }
    __syncthreads();   // barrier B: gtX/gtH ready
    // ---- phase 2 ----
    if (half == 0) {
      // epilogue: 256 threads cover the 16x16 (row, h-col) tile once
      float av_i = gtX[0][er][ej] + gtH[0][er][ej] + b_i;
      float av_f = gtX[1][er][ej] + gtH[1][er][ej] + b_f;
      float av_o = gtX[2][er][ej] + gtH[2][er][ej] + b_o;
      float av_g = gtX[3][er][ej] + gtH[3][er][ej] + b_g;
      float iv = 1.f / (1.f + expf(-av_i));
      float fv = 1.f / (1.f + expf(-av_f));
      float ov = 1.f / (1.f + expf(-av_o));
      float gv = tanhf(av_g);
      float cn = fv * creg + iv * gv;
      creg = cn;
      float hv = ov * tanhf(cn);
      out[((size_t)rg * T_T + t) * 1024 + hcol] = hv;
      union { __hip_bfloat16 b; unsigned short s; } cv;
      cv.b = __float2bfloat16(hv);
      unsigned hvu = cv.s;
      __hip_bfloat16* hd = hb + ((size_t)((t + 1) & 1) << 16) + (size_t)rg * 1024 + hcol;
      asm volatile("global_store_short %0, %1, off sc0 sc1" :: "v"(hd), "v"(hvu) : "memory");
      asm volatile("s_waitcnt vmcnt(0)" ::: "memory");   // this wave's stores acked
      if (lane == 0)
        __hip_atomic_fetch_add(flags + ((unsigned)t << 8) + ((unsigned)bg << 6) + cgrp,
                               1u, __ATOMIC_RELAXED, __HIP_MEMORY_SCOPE_AGENT);
      // prefetch xb_{t+1} -> AX[(t+1)&1] (plain cached loads; consumed after barrier A)
      if (t + 1 < T_T) {
        const u32x4* src = (const u32x4*)(xb + ((size_t)(t + 1) * 64 + rows0) * 1024);
        #pragma unroll
        for (int p = 0; p < 8; ++p) {
          int r = (p << 1) + (tid2 >> 7), c8 = tid2 & 127;
          u32x4 v = src[r * 128 + c8];
          *(u32x4*)&AX[(t + 1) & 1][r][c8 << 3] = v;
        }
      }
    } else if (t + 1 < T_T) {
      // h-waves: each wave spins independently on this bg's 64 producer flags
      {
        unsigned* fp = flags + ((unsigned)t << 8) + ((unsigned)bg << 6) + lane;
        int spun = 0;
        while (!poison) {
          unsigned v = __hip_atomic_load(fp, __ATOMIC_RELAXED, __HIP_MEMORY_SCOPE_AGENT);
          if (__all(v == 4u)) break;
          __builtin_amdgcn_s_sleep(1);
          if (++spun > (1 << 16)) poison = 1;   // fast bail -> wrong answer, not a hang
        }
      }
      // load h_t with L2 bypass (written by other XCDs) and stage into AH
      {
        const __hip_bfloat16* hsrc = hb + ((size_t)((t + 1) & 1) << 16);
        const char* base = (const char*)(hsrc + (size_t)rows0 * 1024)
                         + ((tid2 & 127) << 4) + ((tid2 >> 7) << 11);
        const char* p0 = base;          const char* p1 = base + 4096;
        const char* p2 = base + 8192;   const char* p3 = base + 12288;
        const char* p4 = base + 16384;  const char* p5 = base + 20480;
        const char* p6 = base + 24576;  const char* p7 = base + 28672;
        u32x4 d0, d1, d2, d3, d4, d5, d6, d7;
        asm volatile(
          "global_load_dwordx4 %0, %8, off sc0 sc1\n\t"
          "global_load_dwordx4 %1, %9, off sc0 sc1\n\t"
          "global_load_dwordx4 %2, %10, off sc0 sc1\n\t"
          "global_load_dwordx4 %3, %11, off sc0 sc1\n\t"
          "global_load_dwordx4 %4, %12, off sc0 sc1\n\t"
          "global_load_dwordx4 %5, %13, off sc0 sc1\n\t"
          "global_load_dwordx4 %6, %14, off sc0 sc1\n\t"
          "global_load_dwordx4 %7, %15, off sc0 sc1\n\t"
          "s_waitcnt vmcnt(0)"
          : "=&v"(d0), "=&v"(d1), "=&v"(d2), "=&v"(d3),
            "=&v"(d4), "=&v"(d5), "=&v"(d6), "=&v"(d7)
          : "v"(p0), "v"(p1), "v"(p2), "v"(p3),
            "v"(p4), "v"(p5), "v"(p6), "v"(p7)
          : "memory");
        int r0 = tid2 >> 7, c8 = tid2 & 127;
        *(u32x4*)&AH[r0 +  0][c8 << 3] = d0;
        *(u32x4*)&AH[r0 +  2][c8 << 3] = d1;
        *(u32x4*)&AH[r0 +  4][c8 << 3] = d2;
        *(u32x4*)&AH[r0 +  6][c8 << 3] = d3;
        *(u32x4*)&AH[r0 +  8][c8 << 3] = d4;
        *(u32x4*)&AH[r0 + 10][c8 << 3] = d5;
        *(u32x4*)&AH[r0 + 12][c8 << 3] = d6;
        *(u32x4*)&AH[r0 + 14][c8 << 3] = d7;
      }
    }
    __syncthreads();   // barrier A: AH(t), AX[(t+1)&1] staged; gt free for rewrite
  }
}

extern "C" void kernel_launch(void* const* d_in, const int* in_sizes, int n_in,
                              void* d_out, int out_size, void* d_ws, size_t ws_size,
                              hipStream_t stream) {
  const float* x    = (const float*)d_in[0];   // (64,512,1024)
  const float* h0   = (const float*)d_in[1];   // (64,1024)
  const float* Wx   = (const float*)d_in[2];   // (1024,4096)
  const float* Wh   = (const float*)d_in[3];   // (1024,4096)
  const float* bias = (const float*)d_in[4];   // (4096)
  float* out = (float*)d_out;

  char* ws = (char*)d_ws;
  __hip_bfloat16* Wt  = (__hip_bfloat16*)ws;                                 // 16 MiB
  __hip_bfloat16* xb  = (__hip_bfloat16*)(ws + ((size_t)16 << 20));          // 64 MiB
  __hip_bfloat16* hbf = (__hip_bfloat16*)(ws + ((size_t)80 << 20));          // 256 KiB
  unsigned* flags     = (unsigned*)(ws + ((size_t)80 << 20) + (1u << 18));   // 512 KiB

  hipLaunchKernelGGL(prep_weights, dim3(2048), dim3(256), 0, stream, Wx, Wh, Wt);
  hipLaunchKernelGGL(prep_xb, dim3(32768), dim3(256), 0, stream, x, xb);
  hipLaunchKernelGGL(prep_state, dim3(256), dim3(256), 0, stream, h0, hbf);
  (void)hipMemsetAsync(flags, 0, (size_t)512 * 4 * 64 * sizeof(unsigned), stream);

  void* kargs[6];
  kargs[0] = (void*)&xb;
  kargs[1] = (void*)&bias;
  kargs[2] = (void*)&Wt;
  kargs[3] = (void*)&hbf;
  kargs[4] = (void*)&out;
  kargs[5] = (void*)&flags;
  (void)hipLaunchCooperativeKernel(lstm_persist, dim3(256), dim3(512), kargs, 0, stream);
}

// Round 5
// 3791.845 us; speedup vs baseline: 1.8658x; 1.8658x over previous
//
#include <hip/hip_runtime.h>
#include <hip/hip_bf16.h>

// LSTM N=64, T=512, D=1024, H=1024 — round 5: fix the handshake protocol.
// Round-4 post-mortem: weights-in-VGPR worked (FETCH 3.54GB -> 0.57GB) but dur ROSE
// (10.1 -> 13.7 us/step): 256 device-scope RMW flag atomics/bg/step + 65536 2-byte
// sc0sc1 h-stores/step = protocol storm. This round:
//   * producer: h -> LDS hrow; LDS counter handshake among x-waves; wave 0 alone does
//     32 coalesced dwordx4 sc0sc1 stores + ONE relaxed flag store per WG (r2-proven).
//   * consumer: h-wave c spins on its 16-producer chunk only and stages its own 256-col
//     slice -> chunk loads overlap straggler wait.
//   * fast-math epilogue (v_exp_f32 / v_rcp_f32 sigmoid+tanh).
// Kept: wfrag in 128 VGPR, x/h wave split, 1032-stride LDS, fast-fail poison.
// ws: Wt 16MB | xb 64MB | hb 2x128KB | flags 512KB

#define T_T 512
#define KTOT 2048

typedef short bf16x8 __attribute__((ext_vector_type(8)));
typedef float f32x4 __attribute__((ext_vector_type(4)));
typedef unsigned u32x4 __attribute__((ext_vector_type(4)));

union B8U { u32x4 u; bf16x8 v; };
union P4 { __hip_bfloat16 h[4]; uint2 u; };

__device__ __forceinline__ float fsig(float x) {
  float e = __builtin_amdgcn_exp2f(-1.442695041f * x);      // e^{-x}
  return __builtin_amdgcn_rcpf(1.f + e);
}
__device__ __forceinline__ float ftanh(float x) {
  float e = __builtin_amdgcn_exp2f(2.885390082f * fabsf(x)); // e^{2|x|} (inf-safe)
  float r = 1.f - 2.f * __builtin_amdgcn_rcpf(e + 1.f);
  return copysignf(r, x);
}

// ---- Wt[a_col][k] = bf16([Wx;Wh][k][a_col]), 4096 x 2048 (proven) ----
__global__ __launch_bounds__(256) void prep_weights(const float* __restrict__ Wx,
                                                    const float* __restrict__ Wh,
                                                    __hip_bfloat16* __restrict__ Wt) {
  __shared__ float tile[64][65];
  int kb = blockIdx.x & 31;
  int cb = blockIdx.x >> 5;
  int k0 = kb << 6, c0 = cb << 6;
  const float* W = (k0 < 1024) ? Wx : Wh;
  int kr0 = k0 & 1023;
  int tid = threadIdx.x;
  int f4 = tid & 15;
  int i0 = tid >> 4;
  for (int p = 0; p < 4; ++p) {
    int i = i0 + (p << 4);
    float4 v = *(const float4*)(W + (size_t)(kr0 + i) * 4096 + c0 + (f4 << 2));
    tile[(f4 << 2) + 0][i] = v.x;
    tile[(f4 << 2) + 1][i] = v.y;
    tile[(f4 << 2) + 2][i] = v.z;
    tile[(f4 << 2) + 3][i] = v.w;
  }
  __syncthreads();
  for (int p = 0; p < 16; ++p) {
    int idx = (p << 8) + tid;
    int kl = idx & 63, cl = idx >> 6;
    Wt[(size_t)(c0 + cl) * KTOT + k0 + kl] = __float2bfloat16(tile[cl][kl]);
  }
}

// ---- x (64,512,1024) f32 -> xb (512,64,1024) bf16 ----
__global__ __launch_bounds__(256) void prep_xb(const float* __restrict__ x,
                                               __hip_bfloat16* __restrict__ xb) {
  int b = blockIdx.x;            // 32768 = 512*64
  int n = b & 63, t = b >> 6;
  const float4* src = (const float4*)(x + ((size_t)n * T_T + t) * 1024);
  __hip_bfloat16* dst = xb + ((size_t)t * 64 + n) * 1024;
  float4 v = src[threadIdx.x];
  P4 pk;
  pk.h[0] = __float2bfloat16(v.x);
  pk.h[1] = __float2bfloat16(v.y);
  pk.h[2] = __float2bfloat16(v.z);
  pk.h[3] = __float2bfloat16(v.w);
  *(uint2*)(dst + (threadIdx.x << 2)) = pk.u;
}

// ---- h0 -> bf16 into hb[0] ----
__global__ __launch_bounds__(256) void prep_state(const float* __restrict__ h0,
                                                  __hip_bfloat16* __restrict__ hb) {
  int i = blockIdx.x * 256 + threadIdx.x;   // 65536
  hb[i] = __float2bfloat16(h0[i]);
}

// ---- persistent LSTM ----
__global__ __launch_bounds__(512, 2) void lstm_persist(
    const __hip_bfloat16* __restrict__ xb,   // (512,64,1024)
    const float* __restrict__ bias,
    const __hip_bfloat16* __restrict__ Wt,   // (4096,2048)
    __hip_bfloat16* hb,                      // [2][64*1024]
    float* __restrict__ out,                 // (64,512,1024)
    unsigned* flags)                         // [512][4][64] single store of 1 each
{
  __shared__ __align__(16) __hip_bfloat16 AX[2][16][1032];  // x tile, double buffer
  __shared__ __align__(16) __hip_bfloat16 AH[16][1032];     // h tile
  __shared__ float gtX[4][16][17];
  __shared__ float gtH[4][16][17];
  __shared__ __align__(16) __hip_bfloat16 hrow[16][16];
  __shared__ unsigned xcnt;

  const int tid  = threadIdx.x;
  const int cgrp = blockIdx.x & 63;   // h-cols [16*cgrp,+16)
  const int bg   = blockIdx.x >> 6;   // batch rows [16*bg,+16)
  const int rows0 = bg << 4;
  const int lane = tid & 63;
  const int wv   = tid >> 6;          // 0..7
  const int gate = wv & 3;
  const int half = wv >> 2;           // 0 = x-part (K 0..1023), 1 = h-part
  const int mcol = lane & 15;
  const int q    = lane >> 4;
  const int tid2 = tid & 255;

  if (tid == 0) xcnt = 0;

  // ---- weight fragments -> registers (32 x u32x4), invariant over t ----
  u32x4 wfrag[32];
  {
    const __hip_bfloat16* wp = Wt
      + ((size_t)(gate << 10) + (cgrp << 4) + mcol) * (size_t)KTOT
      + (half << 10) + (q << 3);
    #pragma unroll
    for (int kk = 0; kk < 32; ++kk)
      wfrag[kk] = *(const u32x4*)(wp + (kk << 5));
  }

  // epilogue identity (x-waves = tid < 256)
  const int er = tid2 >> 4, ej = tid2 & 15;
  const int hcol = (cgrp << 4) + ej;
  const int rg = rows0 + er;
  float b_i = 0.f, b_f = 0.f, b_o = 0.f, b_g = 0.f;
  if (half == 0) {
    b_i = bias[hcol]; b_f = bias[1024 + hcol];
    b_o = bias[2048 + hcol]; b_g = bias[3072 + hcol];
  }
  float creg = 0.f;
  int poison = 0;

  // ---- prologue: x-waves stage xb_0 -> AX[0]; h-waves stage h0 -> AH ----
  if (half == 0) {
    const u32x4* src = (const u32x4*)(xb + (size_t)rows0 * 1024);
    #pragma unroll
    for (int p = 0; p < 8; ++p) {
      int r = (p << 1) + (tid2 >> 7), c8 = tid2 & 127;
      u32x4 v = src[r * 128 + c8];
      *(u32x4*)&AX[0][r][c8 << 3] = v;
    }
  } else {
    const u32x4* src = (const u32x4*)(hb + (size_t)rows0 * 1024);
    #pragma unroll
    for (int p = 0; p < 8; ++p) {
      int r = (p << 1) + (tid2 >> 7), c8 = tid2 & 127;
      u32x4 v = src[r * 128 + c8];
      *(u32x4*)&AH[r][c8 << 3] = v;
    }
  }
  __syncthreads();

  for (int t = 0; t < T_T; ++t) {
    // ---- phase 1: both GEMMs (LDS A-tile x reg-resident weights) ----
    {
      const __hip_bfloat16* L = (half == 0) ? &AX[t & 1][0][0] : &AH[0][0];
      f32x4 acc = {0.f, 0.f, 0.f, 0.f};
      #pragma unroll
      for (int kk = 0; kk < 32; ++kk) {
        B8U a, b;
        a.u = *(const u32x4*)(L + (size_t)mcol * 1032 + (kk << 5) + (q << 3));
        b.u = wfrag[kk];
        acc = __builtin_amdgcn_mfma_f32_16x16x32_bf16(a.v, b.v, acc, 0, 0, 0);
      }
      float (*gt)[16][17] = (half == 0) ? gtX : gtH;
      #pragma unroll
      for (int i = 0; i < 4; ++i)
        gt[gate][(q << 2) + i][mcol] = acc[i];
    }
    __syncthreads();   // barrier B: gtX/gtH ready
    // ---- phase 2 ----
    if (half == 0) {
      // epilogue: 256 threads cover the 16x16 (row, h-col) tile
      float av_i = gtX[0][er][ej] + gtH[0][er][ej] + b_i;
      float av_f = gtX[1][er][ej] + gtH[1][er][ej] + b_f;
      float av_o = gtX[2][er][ej] + gtH[2][er][ej] + b_o;
      float av_g = gtX[3][er][ej] + gtH[3][er][ej] + b_g;
      float iv = fsig(av_i), fv = fsig(av_f), ov = fsig(av_o);
      float gv = ftanh(av_g);
      float cn = fv * creg + iv * gv;
      creg = cn;
      float hv = ov * ftanh(cn);
      out[((size_t)rg * T_T + t) * 1024 + hcol] = hv;
      hrow[er][ej] = __float2bfloat16(hv);
      // intra-x-wave handshake: DS ops are in-order per wave, so the hrow write of
      // this wave is complete before its counter bump is visible.
      if (lane == 0)
        __hip_atomic_fetch_add(&xcnt, 1u, __ATOMIC_RELAXED, __HIP_MEMORY_SCOPE_WORKGROUP);
      if (wv == 0) {
        int spun = 0;
        while (!poison) {
          unsigned v = __hip_atomic_load(&xcnt, __ATOMIC_RELAXED,
                                         __HIP_MEMORY_SCOPE_WORKGROUP);
          if (v == 4u) break;
          if (++spun > (1 << 20)) poison = 1;
        }
        if (lane < 32) {   // 16x16 bf16 tile = 32 coalesced dwordx4 device-scope stores
          u32x4 v = *(const u32x4*)&hrow[lane >> 1][(lane & 1) << 3];
          __hip_bfloat16* hd = hb + ((size_t)((t + 1) & 1) << 16)
                             + (size_t)(rows0 + (lane >> 1)) * 1024
                             + (cgrp << 4) + ((lane & 1) << 3);
          asm volatile("global_store_dwordx4 %0, %1, off sc0 sc1"
                       :: "v"(hd), "v"(v) : "memory");
        }
        asm volatile("s_waitcnt vmcnt(0)" ::: "memory");   // h stores acked at L3
        if (lane == 0) {
          __hip_atomic_store(&xcnt, 0u, __ATOMIC_RELAXED, __HIP_MEMORY_SCOPE_WORKGROUP);
          __hip_atomic_store(flags + ((unsigned)t << 8) + ((unsigned)bg << 6) + cgrp, 1u,
                             __ATOMIC_RELAXED, __HIP_MEMORY_SCOPE_AGENT);
        }
      }
      // prefetch xb_{t+1} -> AX[(t+1)&1] (plain cached loads; consumed after barrier A)
      if (t + 1 < T_T) {
        const u32x4* src = (const u32x4*)(xb + ((size_t)(t + 1) * 64 + rows0) * 1024);
        #pragma unroll
        for (int p = 0; p < 8; ++p) {
          int r = (p << 1) + (tid2 >> 7), c8 = tid2 & 127;
          u32x4 v = src[r * 128 + c8];
          *(u32x4*)&AX[(t + 1) & 1][r][c8 << 3] = v;
        }
      }
    } else if (t + 1 < T_T) {
      // h-wave c: spin on its own 16-producer chunk, then stage that 256-col slice.
      const int chunk = wv - 4;           // 0..3 -> h-cols [256*chunk, +256)
      {
        unsigned* fp = flags + ((unsigned)t << 8) + ((unsigned)bg << 6)
                     + (chunk << 4) + (lane & 15);
        int spun = 0;
        while (!poison) {
          unsigned v = __hip_atomic_load(fp, __ATOMIC_RELAXED, __HIP_MEMORY_SCOPE_AGENT);
          if (__all(v != 0)) break;
          __builtin_amdgcn_s_sleep(1);
          if (++spun > (1 << 16)) poison = 1;   // fast bail -> wrong answer, not hang
        }
      }
      {
        const __hip_bfloat16* hsrc = hb + ((size_t)((t + 1) & 1) << 16);
        const int c8 = lane & 31;         // 8-elem group within chunk
        const int r0 = lane >> 5;         // 0..1; rows r0+2k, k=0..7
        const char* base = (const char*)(hsrc + (size_t)(rows0 + r0) * 1024
                                         + (chunk << 8) + (c8 << 3));
        const char* p0 = base;          const char* p1 = base + 4096;
        const char* p2 = base + 8192;   const char* p3 = base + 12288;
        const char* p4 = base + 16384;  const char* p5 = base + 20480;
        const char* p6 = base + 24576;  const char* p7 = base + 28672;
        u32x4 d0, d1, d2, d3, d4, d5, d6, d7;
        asm volatile(
          "global_load_dwordx4 %0, %8, off sc0 sc1\n\t"
          "global_load_dwordx4 %1, %9, off sc0 sc1\n\t"
          "global_load_dwordx4 %2, %10, off sc0 sc1\n\t"
          "global_load_dwordx4 %3, %11, off sc0 sc1\n\t"
          "global_load_dwordx4 %4, %12, off sc0 sc1\n\t"
          "global_load_dwordx4 %5, %13, off sc0 sc1\n\t"
          "global_load_dwordx4 %6, %14, off sc0 sc1\n\t"
          "global_load_dwordx4 %7, %15, off sc0 sc1\n\t"
          "s_waitcnt vmcnt(0)"
          : "=&v"(d0), "=&v"(d1), "=&v"(d2), "=&v"(d3),
            "=&v"(d4), "=&v"(d5), "=&v"(d6), "=&v"(d7)
          : "v"(p0), "v"(p1), "v"(p2), "v"(p3),
            "v"(p4), "v"(p5), "v"(p6), "v"(p7)
          : "memory");
        const int cc = (chunk << 8) + (c8 << 3);
        *(u32x4*)&AH[r0 +  0][cc] = d0;
        *(u32x4*)&AH[r0 +  2][cc] = d1;
        *(u32x4*)&AH[r0 +  4][cc] = d2;
        *(u32x4*)&AH[r0 +  6][cc] = d3;
        *(u32x4*)&AH[r0 +  8][cc] = d4;
        *(u32x4*)&AH[r0 + 10][cc] = d5;
        *(u32x4*)&AH[r0 + 12][cc] = d6;
        *(u32x4*)&AH[r0 + 14][cc] = d7;
      }
    }
    __syncthreads();   // barrier A: AH(t), AX[(t+1)&1] staged; gt free for rewrite
  }
}

extern "C" void kernel_launch(void* const* d_in, const int* in_sizes, int n_in,
                              void* d_out, int out_size, void* d_ws, size_t ws_size,
                              hipStream_t stream) {
  const float* x    = (const float*)d_in[0];   // (64,512,1024)
  const float* h0   = (const float*)d_in[1];   // (64,1024)
  const float* Wx   = (const float*)d_in[2];   // (1024,4096)
  const float* Wh   = (const float*)d_in[3];   // (1024,4096)
  const float* bias = (const float*)d_in[4];   // (4096)
  float* out = (float*)d_out;

  char* ws = (char*)d_ws;
  __hip_bfloat16* Wt  = (__hip_bfloat16*)ws;                                 // 16 MiB
  __hip_bfloat16* xb  = (__hip_bfloat16*)(ws + ((size_t)16 << 20));          // 64 MiB
  __hip_bfloat16* hbf = (__hip_bfloat16*)(ws + ((size_t)80 << 20));          // 256 KiB
  unsigned* flags     = (unsigned*)(ws + ((size_t)80 << 20) + (1u << 18));   // 512 KiB

  hipLaunchKernelGGL(prep_weights, dim3(2048), dim3(256), 0, stream, Wx, Wh, Wt);
  hipLaunchKernelGGL(prep_xb, dim3(32768), dim3(256), 0, stream, x, xb);
  hipLaunchKernelGGL(prep_state, dim3(256), dim3(256), 0, stream, h0, hbf);
  (void)hipMemsetAsync(flags, 0, (size_t)512 * 4 * 64 * sizeof(unsigned), stream);

  void* kargs[6];
  kargs[0] = (void*)&xb;
  kargs[1] = (void*)&bias;
  kargs[2] = (void*)&Wt;
  kargs[3] = (void*)&hbf;
  kargs[4] = (void*)&out;
  kargs[5] = (void*)&flags;
  (void)hipLaunchCooperativeKernel(lstm_persist, dim3(256), dim3(512), kargs, 0, stream);
}